// Round 2
// baseline (257.967 us; speedup 1.0000x reference)
//
#include <hip/hip_runtime.h>
#include <stdint.h>

#define DIM   1024
#define L_SEQ 2048
#define BATCH 2
#define NH    8
#define M_TOT 4096   // BATCH * L_SEQ
#define EPS_F 1e-5f

typedef __bf16 bf16x8 __attribute__((ext_vector_type(8)));
typedef unsigned short u16x8 __attribute__((ext_vector_type(8)));
typedef float f32x4 __attribute__((ext_vector_type(4)));

__device__ __forceinline__ unsigned short f2bf(float f) {
  unsigned int u = __float_as_uint(f);
  u += 0x7FFFu + ((u >> 16) & 1u);   // RNE
  return (unsigned short)(u >> 16);
}

__device__ __forceinline__ f32x4 mfma_bf16(u16x8 a, u16x8 b, f32x4 c) {
  return __builtin_amdgcn_mfma_f32_16x16x32_bf16(
      __builtin_bit_cast(bf16x8, a), __builtin_bit_cast(bf16x8, b), c, 0, 0, 0);
}

__device__ __forceinline__ float silu_f(float v) {
  return v / (1.f + __expf(-v));
}

// async global -> LDS, 16 bytes per lane (global_load_lds_dwordx4)
__device__ __forceinline__ void gload16(const unsigned short* g, unsigned short* l) {
  __builtin_amdgcn_global_load_lds(
      (const __attribute__((address_space(1))) unsigned int*)g,
      (__attribute__((address_space(3))) unsigned int*)l, 16, 0, 0);
}

// ============================================================================
// R16: manual co-resident grid barrier (plain <<<>>> launches, graph-safe).
// R15's hipLaunchCooperativeKernel was silently rejected (poison survived in
// the timing path; zeros in the pytest path => kernels never ran). Same fused
// structure, standard spin barrier with agent-scope fences:
//   release: __threadfence() emits L2 writeback (cross-XCD publish)
//   acquire: __threadfence() emits L2 invalidate (cross-XCD observe)
// Counters in workspace, zeroed by a 256B hipMemsetAsync each launch (the
// workspace is poison-filled by the harness每 iteration, so zeroing is
// mandatory). Co-residency: coop_main 768 blocks, bounds(256,4) + 33.2KB LDS
// => 4 blocks/CU capacity >= 768/256 = 3 needed. coop_tail 256 blocks.
// ============================================================================

__device__ __forceinline__ void grid_bar(unsigned int* cnt, unsigned int target) {
  __syncthreads();
  if (threadIdx.x == 0) {
    __threadfence();   // agent-scope release: write back L2
    __hip_atomic_fetch_add(cnt, 1u, __ATOMIC_RELAXED, __HIP_MEMORY_SCOPE_AGENT);
    while (__hip_atomic_load(cnt, __ATOMIC_RELAXED, __HIP_MEMORY_SCOPE_AGENT) < target) {
      __builtin_amdgcn_s_sleep(8);
    }
    __threadfence();   // agent-scope acquire: invalidate stale lines
  }
  __syncthreads();
}

__global__ __launch_bounds__(256, 4) void coop_main(
    const float*  __restrict__ x,
    const float*  __restrict__ W_dt,
    const float*  __restrict__ b_dt,
    const float*  __restrict__ ln_a,
    const float4* __restrict__ wz4,
    const float4* __restrict__ wza4,
    const float4* __restrict__ wya4,
    float*        __restrict__ ln_da,
    unsigned short* __restrict__ xb,
    float*        __restrict__ Zs,
    const float*  __restrict__ b_z,
    const float*  __restrict__ b_za,
    const float*  __restrict__ b_ya,
    float*        __restrict__ wdiag,
    float*        __restrict__ y,      // Sy written here by gemm y-blocks
    unsigned short* __restrict__ Wzb,
    unsigned short* __restrict__ Wzab,
    unsigned short* __restrict__ Wyab,
    unsigned int*  __restrict__ bars) {
  __shared__ __align__(16) unsigned short As[128 * 64];   // 16 KB
  __shared__ __align__(16) unsigned short Bs[128 * 64];   // 16 KB
  __shared__ float colsum[64];
  __shared__ float partials[NH][4];

  const int tid = threadIdx.x;
  const int blk = blockIdx.x;           // 0..767
  const int lane = tid & 63, wave = tid >> 6;

  // ---------------- phase P: prep (weights -> bf16, x -> bf16 + dt dot) ----
  {
    ushort4* wzb4  = (ushort4*)Wzb;
    ushort4* wzab4 = (ushort4*)Wzab;
    ushort4* wyab4 = (ushort4*)Wyab;
#pragma unroll
    for (int it = 0; it < 4; ++it) {
      const int i = it * 196608 + blk * 256 + tid;   // 0..786431
      const float4* s; ushort4* d; int j;
      if (i < 262144)      { s = wz4;  d = wzb4;  j = i; }
      else if (i < 524288) { s = wza4; d = wzab4; j = i - 262144; }
      else                 { s = wya4; d = wyab4; j = i - 524288; }
      float4 f = s[j];
      d[j] = make_ushort4(f2bf(f.x), f2bf(f.y), f2bf(f.z), f2bf(f.w));
    }
    if (blk == 0) {   // Zs accumulator zero (consumed by gemm-z atomics)
      ((f32x4*)Zs)[tid]       = f32x4{0.f, 0.f, 0.f, 0.f};
      ((f32x4*)Zs)[tid + 256] = f32x4{0.f, 0.f, 0.f, 0.f};
    }
    // x rows: 4096 rows grid-strided over 768 blocks
    for (int it = 0; it < 6; ++it) {
      const int row = it * 768 + blk;
      if (row < 4096) {
        float4 f = ((const float4*)(x + (size_t)row * DIM))[tid];
        ((ushort4*)(xb + (size_t)row * DIM))[tid] =
            make_ushort4(f2bf(f.x), f2bf(f.y), f2bf(f.z), f2bf(f.w));
#pragma unroll
        for (int h = 0; h < NH; ++h) {
          const float4 w = ((const float4*)(W_dt + (size_t)h * DIM))[tid];
          float p = f.x * w.x + f.y * w.y + f.z * w.z + f.w * w.w;
          for (int off = 32; off > 0; off >>= 1) p += __shfl_down(p, off);
          if (lane == 0) partials[h][wave] = p;
        }
        __syncthreads();
        if (tid < 32) {
          const int h = tid >> 2, wv = tid & 3;
          float s = partials[h][wv];
          s += __shfl_down(s, 1);
          s += __shfl_down(s, 2);
          if (wv == 0) {
            float t = s + b_dt[h];
            float sp = (t > 20.f) ? t : log1pf(expf(t));
            int b = row >> 11, l = row & (L_SEQ - 1);
            ln_da[(size_t)(b * NH + h) * L_SEQ + l] = -expf(ln_a[h]) * sp;
          }
        }
        __syncthreads();   // partials WAR before next row
      }
    }
  }

  grid_bar(bars + 0, 768u);

  // ---------------- phase G: merged GEMM (verbatim from tuned gemm_all) ----
  {
    const int wm = wave >> 1, wn = wave & 1;
    const int l16 = lane & 15, quad = lane >> 4;

    const int flat = blk;
    const int xcd = flat & 7;
    const int j = flat >> 3;
    const int nt = 3 * xcd + (j % 3);            // 0..23, 3 per XCD
    const int mt = j / 3;                        // 0..31
    const bool isZ = (nt < 16);
    const int n0 = isZ ? nt * 64 : (nt - 16) * 128;
    const int m0 = mt * 128;

    const int rowl = tid >> 3;                   // 0..31
    const int g = (tid & 7) ^ (rowl & 7);        // XOR-swizzled k-chunk
    const size_t aoff = (size_t)(m0 + rowl) * DIM + g * 8;
    const size_t boff = (size_t)(n0 + rowl) * DIM + g * 8;
    const unsigned short* bp0 = isZ ? Wzb : Wyab;                        // slots 0,1
    const unsigned short* bp1 = isZ ? Wzab : (Wyab + (size_t)64 * DIM);  // slots 2,3
    unsigned short* AsD = As + tid * 8;
    unsigned short* BsD = Bs + tid * 8;

    f32x4 acc[4][4];
    const f32x4 zero = {0.f, 0.f, 0.f, 0.f};
    for (int i = 0; i < 4; ++i)
      for (int jj = 0; jj < 4; ++jj) acc[i][jj] = zero;

    for (int kt = 0; kt < 16; ++kt) {
      const size_t k0 = (size_t)kt * 64;
      __syncthreads();
      gload16(xb  + aoff + k0,                AsD);
      gload16(xb  + aoff + 32 * DIM + k0,     AsD + 2048);
      gload16(xb  + aoff + 64 * DIM + k0,     AsD + 4096);
      gload16(xb  + aoff + 96 * DIM + k0,     AsD + 6144);
      gload16(bp0 + boff + k0,                BsD);
      gload16(bp0 + boff + 32 * DIM + k0,     BsD + 2048);
      gload16(bp1 + boff + k0,                BsD + 4096);
      gload16(bp1 + boff + 32 * DIM + k0,     BsD + 6144);
      __syncthreads();   // drains vmcnt(0): staged data visible
#pragma unroll
      for (int kk = 0; kk < 2; ++kk) {
        const int kc = kk * 4 + quad;
        u16x8 aF[4], bF[4];
#pragma unroll
        for (int rb = 0; rb < 4; ++rb) {
          const int r = wm * 64 + rb * 16 + l16;
          aF[rb] = *(const u16x8*)&As[r * 64 + ((kc ^ (r & 7)) << 3)];
        }
#pragma unroll
        for (int cb = 0; cb < 4; ++cb) {
          int r;
          if (isZ) r = (cb < 2) ? (wn * 32 + cb * 16 + l16)
                                : (64 + wn * 32 + (cb - 2) * 16 + l16);
          else     r = wn * 64 + cb * 16 + l16;
          bF[cb] = *(const u16x8*)&Bs[r * 64 + ((kc ^ (r & 7)) << 3)];
        }
#pragma unroll
        for (int rb = 0; rb < 4; ++rb)
#pragma unroll
          for (int cb = 0; cb < 4; ++cb)
            acc[rb][cb] = mfma_bf16(aF[rb], bF[cb], acc[rb][cb]);
      }
    }

    if (isZ) {
      __syncthreads();
      if (tid < 64) colsum[tid] = 0.f;
      __syncthreads();
      const int b = m0 >> 11;
#pragma unroll
      for (int cb = 0; cb < 2; ++cb) {
        const int nl = wn * 32 + cb * 16 + l16;       // 0..63
        const int n = n0 + nl;
        const int h = n >> 7;
        const float bz = b_z[n], ba = b_za[n];
        float ssum = 0.f;
#pragma unroll
        for (int rb = 0; rb < 4; ++rb) {
          const int mlb = wm * 64 + rb * 16 + quad * 4;
#pragma unroll
          for (int r = 0; r < 4; ++r) {
            const int l = (m0 + mlb + r) & (L_SEQ - 1);
            float u  = acc[rb][cb][r] + bz;
            float vv = acc[rb][cb + 2][r] + ba;
            if (l > h) ssum += u * silu_f(vv);
            else if (l == h)
              wdiag[(size_t)(b * NH + h) * 128 + (n & 127)] = u * silu_f(vv);
          }
        }
        atomicAdd(&colsum[nl], ssum);
      }
      __syncthreads();
      if (tid < 64) atomicAdd(&Zs[(size_t)b * DIM + n0 + tid], colsum[tid]);
    } else {
#pragma unroll
      for (int cb = 0; cb < 4; ++cb) {
        const int nl = wn * 64 + cb * 16 + l16;       // 0..127
        const float bb = b_ya[n0 + nl];
#pragma unroll
        for (int rb = 0; rb < 4; ++rb) {
          const int mlb = wm * 64 + rb * 16 + quad * 4;
#pragma unroll
          for (int r = 0; r < 4; ++r)
            y[(size_t)(m0 + mlb + r) * DIM + n0 + nl] = silu_f(acc[rb][cb][r] + bb);
        }
      }
    }
  }
}

// ---- tail: stats+scan (blocks 0..15) -> proj (all 256) -> finalize (all 256)
__global__ __launch_bounds__(256) void coop_tail(
    const float* __restrict__ Zs,
    const float* __restrict__ hidden,
    const float* __restrict__ wdiag,
    const float* __restrict__ gn_w,
    const float* __restrict__ ln_da,
    float* __restrict__ vtg,
    float* __restrict__ wtg,
    float* __restrict__ alpha2,
    float* __restrict__ hidden_next,
    const float* __restrict__ W_y,
    const float* __restrict__ gn_b,
    const float* __restrict__ b_y,
    float* __restrict__ Gv,
    float* __restrict__ Gw,
    float* __restrict__ constc,
    float* __restrict__ y,
    unsigned int* __restrict__ bars) {
  const int tid = threadIdx.x;
  const int blk = blockIdx.x;
  __shared__ float csumS[32];
  __shared__ float statS[4];   // svv, svw, sww, total
  __shared__ float aS[64 * 16];

  // ---------------- phase S: stats + 4-wave parallel scan (verbatim) ------
  if (blk < 16) {
    const int bh = blk, b = bh >> 3, h = bh & 7;
    const int wv = tid >> 6, lane = tid & 63;

    float v0 = 0.f, v1 = 0.f, w0 = 0.f, w1 = 0.f;
    const size_t base = (size_t)bh * 128;
    if (wv == 0) {
      v0 = Zs[(size_t)b * DIM + h * 128 + lane]      + hidden[base + lane];
      v1 = Zs[(size_t)b * DIM + h * 128 + 64 + lane] + hidden[base + 64 + lane];
      w0 = wdiag[base + lane];
      w1 = wdiag[base + 64 + lane];
      float sv = v0 + v1, sw = w0 + w1;
      for (int off = 32; off > 0; off >>= 1) {
        sv += __shfl_down(sv, off);
        sw += __shfl_down(sw, off);
      }
      const float muv = __shfl(sv, 0) * (1.f / 128.f);
      const float muw = __shfl(sw, 0) * (1.f / 128.f);
      const float a0 = v0 - muv, a1 = v1 - muv;
      const float c0 = w0 - muw, c1 = w1 - muw;
      float rvv = a0 * a0 + a1 * a1;
      float rvw = a0 * c0 + a1 * c1;
      float rww = c0 * c0 + c1 * c1;
      for (int off = 32; off > 0; off >>= 1) {
        rvv += __shfl_down(rvv, off);
        rvw += __shfl_down(rvw, off);
        rww += __shfl_down(rww, off);
      }
      if (lane == 0) {
        statS[0] = rvv * (1.f / 128.f);
        statS[1] = rvw * (1.f / 128.f);
        statS[2] = rww * (1.f / 128.f);
      }
      const float gw = gn_w[h];
      vtg[base + lane] = a0 * gw;  vtg[base + 64 + lane] = a1 * gw;
      wtg[base + lane] = c0 * gw;  wtg[base + 64 + lane] = c1 * gw;
    }

    const float* src = ln_da + (size_t)bh * L_SEQ;
    float vals[8];
#pragma unroll
    for (int jj = 0; jj < 8; ++jj) {
      const int c = wv * 8 + jj;
      float val = src[c * 64 + lane];
#pragma unroll
      for (int off = 1; off < 64; off <<= 1) {
        float nv = __shfl_up(val, off);
        if (lane >= off) val += nv;
      }
      vals[jj] = val;
      if (lane == 63) csumS[c] = val;
    }
    __syncthreads();

    if (tid < 32) {
      float s = csumS[tid];
      float incl = s;
#pragma unroll
      for (int off = 1; off < 32; off <<= 1) {
        float nv = __shfl_up(incl, off);
        if (tid >= off) incl += nv;
      }
      csumS[tid] = incl - s;            // exclusive carry
      if (tid == 31) statS[3] = incl;   // grand total
    }
    __syncthreads();

    const float svv = statS[0], svw = statS[1], sww = statS[2];
#pragma unroll
    for (int jj = 0; jj < 8; ++jj) {
      const int c = wv * 8 + jj;
      const float S = csumS[c] + vals[jj];
      const float ce = expf(S);
      const float D = rsqrtf(ce * ce * svv + 2.f * ce * svw + sww + EPS_F);
      const int l = c * 64 + lane;
      float* ap = alpha2 + ((size_t)(b * L_SEQ + l) * NH + h) * 2;
      ap[0] = ce * D;
      ap[1] = D;
    }
    if (wv == 0) {
      const float clast = expf(statS[3]);
      hidden_next[base + lane]      = clast * v0 + w0;
      hidden_next[base + 64 + lane] = clast * v1 + w1;
    }
  }

  grid_bar(bars + 1, 256u);

  // ---------------- phase J: proj (verbatim; n = blk*4 + wave) ------------
  {
    const int wave = tid >> 6, lane = tid & 63;
    const int n = blk * 4 + wave;
    const float4* row = (const float4*)(W_y + (size_t)n * DIM);
    const int half = lane >> 5, l32 = lane & 31;
    float cc = 0.f;
#pragma unroll
    for (int p = 0; p < 4; ++p) {
      const int h = p * 2 + half;
      float4 wv = row[p * 64 + lane];
      const float4 va = *(const float4*)&vtg[(size_t)h * 128 + l32 * 4];
      const float4 vb = *(const float4*)&vtg[(size_t)(8 + h) * 128 + l32 * 4];
      const float4 wa = *(const float4*)&wtg[(size_t)h * 128 + l32 * 4];
      const float4 wb = *(const float4*)&wtg[(size_t)(8 + h) * 128 + l32 * 4];
      float gv0 = wv.x * va.x + wv.y * va.y + wv.z * va.z + wv.w * va.w;
      float gv1 = wv.x * vb.x + wv.y * vb.y + wv.z * vb.z + wv.w * vb.w;
      float gw0 = wv.x * wa.x + wv.y * wa.y + wv.z * wa.z + wv.w * wa.w;
      float gw1 = wv.x * wb.x + wv.y * wb.y + wv.z * wb.z + wv.w * wb.w;
      cc += (wv.x + wv.y + wv.z + wv.w) * gn_b[h];
#pragma unroll
      for (int off = 16; off > 0; off >>= 1) {
        gv0 += __shfl_down(gv0, off, 32);
        gv1 += __shfl_down(gv1, off, 32);
        gw0 += __shfl_down(gw0, off, 32);
        gw1 += __shfl_down(gw1, off, 32);
      }
      if (l32 == 0) {
        Gv[(size_t)h * DIM + n]       = gv0;
        Gv[(size_t)(8 + h) * DIM + n] = gv1;
        Gw[(size_t)h * DIM + n]       = gw0;
        Gw[(size_t)(8 + h) * DIM + n] = gw1;
      }
    }
    for (int off = 32; off > 0; off >>= 1) cc += __shfl_down(cc, off);
    if (lane == 0) constc[n] = b_y[n] + cc;
  }

  grid_bar(bars + 2, 256u);

  // ---------------- phase F: finalize (verbatim; flat 256-block map) ------
  {
    const int n0 = (blk & 3) * 256;
    const int m0 = (blk >> 2) * 64;
    const int b = m0 >> 11;
    ((float4*)aS)[tid] = ((const float4*)(alpha2 + (size_t)m0 * 16))[tid];
    __syncthreads();
    const int c = tid & 63;     // col4 within n-tile
    const int rg = tid >> 6;    // row group (16 rows each)
    const int n = n0 + c * 4;
    f32x4 g[16 * 2];
#pragma unroll
    for (int h = 0; h < 8; ++h) {
      g[2 * h]     = *(const f32x4*)&Gv[(size_t)(b * NH + h) * DIM + n];
      g[2 * h + 1] = *(const f32x4*)&Gw[(size_t)(b * NH + h) * DIM + n];
    }
    const f32x4 cc = *(const f32x4*)&constc[n];
#pragma unroll
    for (int jj = 0; jj < 16; ++jj) {
      const int m = m0 + rg * 16 + jj;
      const float* a = &aS[(rg * 16 + jj) * 16];
      f32x4 Ay = cc;
#pragma unroll
      for (int k = 0; k < 16; ++k) Ay += a[k] * g[k];
      f32x4 s = *(const f32x4*)&y[(size_t)m * DIM + n];
      *(f32x4*)&y[(size_t)m * DIM + n] = Ay * s;
    }
  }
}

extern "C" void kernel_launch(void* const* d_in, const int* in_sizes, int n_in,
                              void* d_out, int out_size, void* d_ws, size_t ws_size,
                              hipStream_t stream) {
  const float* x      = (const float*)d_in[0];
  const float* hidden = (const float*)d_in[1];
  const float* W_z    = (const float*)d_in[2];
  const float* b_z    = (const float*)d_in[3];
  const float* W_za   = (const float*)d_in[4];
  const float* b_za   = (const float*)d_in[5];
  const float* W_y    = (const float*)d_in[6];
  const float* b_y    = (const float*)d_in[7];
  const float* W_ya   = (const float*)d_in[8];
  const float* b_ya   = (const float*)d_in[9];
  const float* W_dt   = (const float*)d_in[10];
  const float* b_dt   = (const float*)d_in[11];
  const float* ln_a   = (const float*)d_in[12];
  const float* gn_w   = (const float*)d_in[13];
  const float* gn_b   = (const float*)d_in[14];

  char* ws = (char*)d_ws;
  unsigned short* xb   = (unsigned short*)(ws);             // 8,388,608 B
  unsigned short* Wzb  = (unsigned short*)(ws + 8388608);   // 2,097,152 B
  unsigned short* Wzab = (unsigned short*)(ws + 10485760);  // 2,097,152 B
  unsigned short* Wyab = (unsigned short*)(ws + 12582912);  // 2,097,152 B
  float* ln_da  = (float*)(ws + 14680064);                  // 131,072 B
  float* Zs     = (float*)(ws + 14811136);                  // 8,192 B
  float* wdiag  = (float*)(ws + 14819328);                  // 8,192 B
  float* vtg    = (float*)(ws + 14827520);                  // 8,192 B
  float* wtg    = (float*)(ws + 14835712);                  // 8,192 B
  float* Gv     = (float*)(ws + 14843904);                  // 65,536 B
  float* Gw     = (float*)(ws + 14909440);                  // 65,536 B
  float* constc = (float*)(ws + 14974976);                  // 4,096 B
  float* alpha2 = (float*)(ws + 14979072);                  // 262,144 B
  unsigned int* bars = (unsigned int*)(ws + 15241216);      // 256 B (barrier counters)

  float* y = (float*)d_out;
  float* hidden_next = y + (size_t)M_TOT * DIM;

  // workspace is poison-filled by the harness each iteration: barrier
  // counters must be zeroed every launch (capture-safe stream memset).
  hipMemsetAsync(bars, 0, 256, stream);

  coop_main<<<768, 256, 0, stream>>>(x, W_dt, b_dt, ln_a,
                                     (const float4*)W_z, (const float4*)W_za,
                                     (const float4*)W_ya,
                                     ln_da, xb, Zs, b_z, b_za, b_ya,
                                     wdiag, y, Wzb, Wzab, Wyab, bars);

  coop_tail<<<256, 256, 0, stream>>>(Zs, hidden, wdiag, gn_w, ln_da,
                                     vtg, wtg, alpha2, hidden_next,
                                     W_y, gn_b, b_y, Gv, Gw, constc, y, bars);
}

// Round 4
// 162.513 us; speedup vs baseline: 1.5874x; 1.5874x over previous
//
#include <hip/hip_runtime.h>
#include <stdint.h>

#define DIM   1024
#define L_SEQ 2048
#define BATCH 2
#define NH    8
#define M_TOT 4096   // BATCH * L_SEQ
#define EPS_F 1e-5f

typedef __bf16 bf16x8 __attribute__((ext_vector_type(8)));
typedef unsigned short u16x8 __attribute__((ext_vector_type(8)));
typedef float f32x4 __attribute__((ext_vector_type(4)));

__device__ __forceinline__ unsigned short f2bf(float f) {
  unsigned int u = __float_as_uint(f);
  u += 0x7FFFu + ((u >> 16) & 1u);   // RNE
  return (unsigned short)(u >> 16);
}

__device__ __forceinline__ f32x4 mfma_bf16(u16x8 a, u16x8 b, f32x4 c) {
  return __builtin_amdgcn_mfma_f32_16x16x32_bf16(
      __builtin_bit_cast(bf16x8, a), __builtin_bit_cast(bf16x8, b), c, 0, 0, 0);
}

__device__ __forceinline__ float silu_f(float v) {
  return v / (1.f + __expf(-v));
}

// async global -> LDS, 16 bytes per lane (global_load_lds_dwordx4)
__device__ __forceinline__ void gload16(const unsigned short* g, unsigned short* l) {
  __builtin_amdgcn_global_load_lds(
      (const __attribute__((address_space(1))) unsigned int*)g,
      (__attribute__((address_space(3))) unsigned int*)l, 16, 0, 0);
}

// ============================================================================
// R18 == R17 resubmit (R17 bench failed on container acquisition, not kernel).
// Structure: 4 dispatches, kernel-boundary coherence only (R16 post-mortem:
// per-block agent fences in a grid spin-barrier cost ~85us — buffer_wbl2/inv
// serialize at the XCD L2s; MfmaUtil 7.6% over 130us proved the GEMM itself
// was unchanged at ~27us / ~955 TF effective). stats_scan is dissolved:
//   - the ln_da scan (alpha2, hidden_next) becomes blocks 0..15 of proj_scan
//   - vtg/wtg are recomputed locally in LDS by every proj block (24KB L2
//     reads + trivial VALU; deterministic identical across blocks)
// No new synchronization anywhere; all cross-block deps cross a kernel
// boundary exactly as in the verified R14 base.
// ============================================================================

// ---- prep: blocks 0..4095 -> dt + x->bf16 (register-resident dot); 4096.. -> weight cvt ----
__global__ __launch_bounds__(256) void prep_kernel(const float* __restrict__ x,
                                                   const float* __restrict__ W_dt,
                                                   const float* __restrict__ b_dt,
                                                   const float* __restrict__ ln_a,
                                                   const float4* __restrict__ wz,
                                                   const float4* __restrict__ wza,
                                                   const float4* __restrict__ wya,
                                                   float* __restrict__ ln_da,
                                                   unsigned short* __restrict__ xb,
                                                   ushort4* __restrict__ wzb,
                                                   ushort4* __restrict__ wzab,
                                                   ushort4* __restrict__ wyab,
                                                   float* __restrict__ Zs) {
  const int blk = blockIdx.x;
  const int tid = threadIdx.x;
  if (blk >= 4096) {
    const int wb = blk - 4096;
    if (wb < 2) ((f32x4*)Zs)[wb * 256 + tid] = f32x4{0.f, 0.f, 0.f, 0.f};
    int i = wb * 256 + tid;                    // 0 .. 786431
    const float4* s; ushort4* d; int j;
    if (i < 262144)      { s = wz;  d = wzb;  j = i; }
    else if (i < 524288) { s = wza; d = wzab; j = i - 262144; }
    else                 { s = wya; d = wyab; j = i - 524288; }
    float4 f = s[j];
    d[j] = make_ushort4(f2bf(f.x), f2bf(f.y), f2bf(f.z), f2bf(f.w));
    return;
  }
  // dt + x->bf16: each thread keeps its 4 x-elements in registers; no xs LDS.
  __shared__ float partials[NH][4];
  const int row = blk;                         // 0..4095
  const int wave = tid >> 6, lane = tid & 63;
  float4 f = ((const float4*)(x + (size_t)row * DIM))[tid];
  ((ushort4*)(xb + (size_t)row * DIM))[tid] =
      make_ushort4(f2bf(f.x), f2bf(f.y), f2bf(f.z), f2bf(f.w));
#pragma unroll
  for (int h = 0; h < NH; ++h) {
    const float4 w = ((const float4*)(W_dt + (size_t)h * DIM))[tid];
    float p = f.x * w.x + f.y * w.y + f.z * w.z + f.w * w.w;
    for (int off = 32; off > 0; off >>= 1) p += __shfl_down(p, off);
    if (lane == 0) partials[h][wave] = p;
  }
  __syncthreads();
  if (tid < 32) {
    const int h = tid >> 2, wv = tid & 3;
    float s = partials[h][wv];
    s += __shfl_down(s, 1);
    s += __shfl_down(s, 2);
    if (wv == 0) {
      float t = s + b_dt[h];
      float sp = (t > 20.f) ? t : log1pf(expf(t));
      int b = row >> 11, l = row & (L_SEQ - 1);
      ln_da[(size_t)(b * NH + h) * L_SEQ + l] = -expf(ln_a[h]) * sp;
    }
  }
}

// ---- merged GEMM, balanced blocks, single-buffer BK=64, lean addressing, XCD-clustered:
//   nt<16 : z-block, M128 x N64, DUAL GEMM (Wz + Wza)  -> colsum/wdiag epilogue
//   nt>=16: y-block, M128 x N128, single GEMM (Wya)    -> Sy = silu(C+b) into d_out
// 1D grid of 768 (3 blocks/CU); flat -> (nt,mt) clusters 3 n-tiles per XCD.
// Verified plateau: ~27us (~955 TF effective incl. dual-GEMM A-sharing;
// MfmaUtil-derived from R16 profile). dbuf/split/A-direct/8-phase all
// rejected (prior ablations + structure math).
__global__ __launch_bounds__(256, 4) void gemm_all(const unsigned short* __restrict__ xb,
                                                   const unsigned short* __restrict__ Wz,
                                                   const unsigned short* __restrict__ Wza,
                                                   const unsigned short* __restrict__ Wya,
                                                   const float* __restrict__ b_z,
                                                   const float* __restrict__ b_za,
                                                   const float* __restrict__ b_ya,
                                                   float* __restrict__ Zs,
                                                   float* __restrict__ wdiag,
                                                   float* __restrict__ Sy) {
  __shared__ __align__(16) unsigned short As[128 * 64];   // 16 KB
  __shared__ __align__(16) unsigned short Bs[128 * 64];   // 16 KB
  __shared__ float colsum[64];

  const int tid = threadIdx.x;
  const int lane = tid & 63, wave = tid >> 6;
  const int wm = wave >> 1, wn = wave & 1;
  const int l16 = lane & 15, quad = lane >> 4;

  const int flat = blockIdx.x;
  const int xcd = flat & 7;
  const int j = flat >> 3;
  const int nt = 3 * xcd + (j % 3);            // 0..23, 3 per XCD
  const int mt = j / 3;                        // 0..31
  const bool isZ = (nt < 16);
  const int n0 = isZ ? nt * 64 : (nt - 16) * 128;
  const int m0 = mt * 128;

  // lean per-lane staging offsets (elements)
  const int rowl = tid >> 3;                   // 0..31
  const int g = (tid & 7) ^ (rowl & 7);        // XOR-swizzled k-chunk
  const size_t aoff = (size_t)(m0 + rowl) * DIM + g * 8;
  const size_t boff = (size_t)(n0 + rowl) * DIM + g * 8;
  const unsigned short* bp0 = isZ ? Wz : Wya;                        // slots 0,1
  const unsigned short* bp1 = isZ ? Wza : (Wya + (size_t)64 * DIM);  // slots 2,3
  unsigned short* AsD = As + tid * 8;
  unsigned short* BsD = Bs + tid * 8;

  f32x4 acc[4][4];
  const f32x4 zero = {0.f, 0.f, 0.f, 0.f};
  for (int i = 0; i < 4; ++i)
    for (int jj = 0; jj < 4; ++jj) acc[i][jj] = zero;

  for (int kt = 0; kt < 16; ++kt) {
    const size_t k0 = (size_t)kt * 64;
    __syncthreads();
    gload16(xb  + aoff + k0,                AsD);
    gload16(xb  + aoff + 32 * DIM + k0,     AsD + 2048);
    gload16(xb  + aoff + 64 * DIM + k0,     AsD + 4096);
    gload16(xb  + aoff + 96 * DIM + k0,     AsD + 6144);
    gload16(bp0 + boff + k0,                BsD);
    gload16(bp0 + boff + 32 * DIM + k0,     BsD + 2048);
    gload16(bp1 + boff + k0,                BsD + 4096);
    gload16(bp1 + boff + 32 * DIM + k0,     BsD + 6144);
    __syncthreads();   // drains vmcnt(0): staged data visible
#pragma unroll
    for (int kk = 0; kk < 2; ++kk) {
      const int kc = kk * 4 + quad;
      u16x8 aF[4], bF[4];
#pragma unroll
      for (int rb = 0; rb < 4; ++rb) {
        const int r = wm * 64 + rb * 16 + l16;
        aF[rb] = *(const u16x8*)&As[r * 64 + ((kc ^ (r & 7)) << 3)];
      }
#pragma unroll
      for (int cb = 0; cb < 4; ++cb) {
        int r;
        if (isZ) r = (cb < 2) ? (wn * 32 + cb * 16 + l16)
                              : (64 + wn * 32 + (cb - 2) * 16 + l16);
        else     r = wn * 64 + cb * 16 + l16;
        bF[cb] = *(const u16x8*)&Bs[r * 64 + ((kc ^ (r & 7)) << 3)];
      }
#pragma unroll
      for (int rb = 0; rb < 4; ++rb)
#pragma unroll
        for (int cb = 0; cb < 4; ++cb)
          acc[rb][cb] = mfma_bf16(aF[rb], bF[cb], acc[rb][cb]);
    }
  }

  if (isZ) {
    // U = acc[.][cb] (cb<2) + b_z, V = acc[.][cb+2] + b_za
    __syncthreads();
    if (tid < 64) colsum[tid] = 0.f;
    __syncthreads();
    const int b = m0 >> 11;
#pragma unroll
    for (int cb = 0; cb < 2; ++cb) {
      const int nl = wn * 32 + cb * 16 + l16;       // 0..63
      const int n = n0 + nl;
      const int h = n >> 7;
      const float bz = b_z[n], ba = b_za[n];
      float ssum = 0.f;
#pragma unroll
      for (int rb = 0; rb < 4; ++rb) {
        const int mlb = wm * 64 + rb * 16 + quad * 4;
#pragma unroll
        for (int r = 0; r < 4; ++r) {
          const int l = (m0 + mlb + r) & (L_SEQ - 1);
          float u  = acc[rb][cb][r] + bz;
          float vv = acc[rb][cb + 2][r] + ba;
          if (l > h) ssum += u * silu_f(vv);
          else if (l == h)
            wdiag[(size_t)(b * NH + h) * 128 + (n & 127)] = u * silu_f(vv);
        }
      }
      atomicAdd(&colsum[nl], ssum);
    }
    __syncthreads();
    if (tid < 64) atomicAdd(&Zs[(size_t)b * DIM + n0 + tid], colsum[tid]);
  } else {
#pragma unroll
    for (int cb = 0; cb < 4; ++cb) {
      const int nl = wn * 64 + cb * 16 + l16;       // 0..127
      const float bb = b_ya[n0 + nl];
#pragma unroll
      for (int rb = 0; rb < 4; ++rb) {
        const int mlb = wm * 64 + rb * 16 + quad * 4;
#pragma unroll
        for (int r = 0; r < 4; ++r)
          Sy[(size_t)(m0 + mlb + r) * DIM + n0 + nl] = silu_f(acc[rb][cb][r] + bb);
      }
    }
  }
}

// ---- merged proj + scan, grid = 272 blocks:
//   blocks 0..15  : per (b,h) scan of ln_da -> alpha2, hidden_next
//                   (stats svv/svw/sww recomputed locally from Zs/wdiag/hidden)
//   blocks 16..271: proj for n = (blk-16)*4 + wave, with vtg/wtg recomputed
//                   locally into LDS (removes the stats->proj global dep)
__global__ __launch_bounds__(256) void proj_scan(const float* __restrict__ Zs,
                                                 const float* __restrict__ hidden,
                                                 const float* __restrict__ wdiag,
                                                 const float* __restrict__ gn_w,
                                                 const float* __restrict__ ln_da,
                                                 float* __restrict__ alpha2,
                                                 float* __restrict__ hidden_next,
                                                 const float* __restrict__ W_y,
                                                 const float* __restrict__ gn_b,
                                                 const float* __restrict__ b_y,
                                                 float* __restrict__ Gv,
                                                 float* __restrict__ Gw,
                                                 float* __restrict__ constc) {
  const int tid = threadIdx.x;
  const int blk = blockIdx.x;
  __shared__ float csumS[32];
  __shared__ float statS[4];        // svv, svw, sww, total
  __shared__ float vtgL[16 * 128];  // 8 KB
  __shared__ float wtgL[16 * 128];  // 8 KB

  if (blk < 16) {
    // ---------------- scan branch (verbatim R14 stats_scan minus vtg/wtg) --
    const int bh = blk, b = bh >> 3;
    const int wv = tid >> 6, lane = tid & 63;

    float v0 = 0.f, v1 = 0.f, w0 = 0.f, w1 = 0.f;
    const size_t base = (size_t)bh * 128;
    if (wv == 0) {
      v0 = Zs[(size_t)b * DIM + (bh & 7) * 128 + lane]      + hidden[base + lane];
      v1 = Zs[(size_t)b * DIM + (bh & 7) * 128 + 64 + lane] + hidden[base + 64 + lane];
      w0 = wdiag[base + lane];
      w1 = wdiag[base + 64 + lane];
      float sv = v0 + v1, sw = w0 + w1;
      for (int off = 32; off > 0; off >>= 1) {
        sv += __shfl_down(sv, off);
        sw += __shfl_down(sw, off);
      }
      const float muv = __shfl(sv, 0) * (1.f / 128.f);
      const float muw = __shfl(sw, 0) * (1.f / 128.f);
      const float a0 = v0 - muv, a1 = v1 - muv;
      const float c0 = w0 - muw, c1 = w1 - muw;
      float rvv = a0 * a0 + a1 * a1;
      float rvw = a0 * c0 + a1 * c1;
      float rww = c0 * c0 + c1 * c1;
      for (int off = 32; off > 0; off >>= 1) {
        rvv += __shfl_down(rvv, off);
        rvw += __shfl_down(rvw, off);
        rww += __shfl_down(rww, off);
      }
      if (lane == 0) {
        statS[0] = rvv * (1.f / 128.f);
        statS[1] = rvw * (1.f / 128.f);
        statS[2] = rww * (1.f / 128.f);
      }
    }

    // phase 1: per-wave intra-chunk inclusive prefix on 8 chunks
    const float* src = ln_da + (size_t)bh * L_SEQ;
    float vals[8];
#pragma unroll
    for (int jj = 0; jj < 8; ++jj) {
      const int c = wv * 8 + jj;
      float val = src[c * 64 + lane];
#pragma unroll
      for (int off = 1; off < 64; off <<= 1) {
        float nv = __shfl_up(val, off);
        if (lane >= off) val += nv;
      }
      vals[jj] = val;
      if (lane == 63) csumS[c] = val;
    }
    __syncthreads();

    // phase 2: wave 0 lanes 0..31: exclusive scan of the 32 chunk totals
    if (tid < 32) {
      float s = csumS[tid];
      float incl = s;
#pragma unroll
      for (int off = 1; off < 32; off <<= 1) {
        float nv = __shfl_up(incl, off);
        if (tid >= off) incl += nv;
      }
      csumS[tid] = incl - s;            // exclusive carry
      if (tid == 31) statS[3] = incl;   // grand total
    }
    __syncthreads();

    // phase 3: apply carries, compute alpha2
    const float svv = statS[0], svw = statS[1], sww = statS[2];
#pragma unroll
    for (int jj = 0; jj < 8; ++jj) {
      const int c = wv * 8 + jj;
      const float S = csumS[c] + vals[jj];
      const float ce = expf(S);
      const float D = rsqrtf(ce * ce * svv + 2.f * ce * svw + sww + EPS_F);
      const int l = c * 64 + lane;
      float* ap = alpha2 + ((size_t)(b * L_SEQ + l) * NH + (bh & 7)) * 2;
      ap[0] = ce * D;
      ap[1] = D;
    }
    if (wv == 0) {
      const float clast = expf(statS[3]);
      hidden_next[base + lane]      = clast * v0 + w0;
      hidden_next[base + 64 + lane] = clast * v1 + w1;
    }
  } else {
    // ---------------- proj branch -----------------------------------------
    // recompute vtg/wtg into LDS: thread t handles bh = t>>4, 8 d's at (t&15)*8
    {
      const int bh16 = tid >> 4, dbase = (tid & 15) * 8;
      const int bq = bh16 >> 3, hq = bh16 & 7;
      const int lane = tid & 63;
      const float4* zp = (const float4*)&Zs[(size_t)bq * DIM + hq * 128 + dbase];
      const float4* hp = (const float4*)&hidden[(size_t)bh16 * 128 + dbase];
      const float4* wp = (const float4*)&wdiag[(size_t)bh16 * 128 + dbase];
      const float4 za = zp[0], zb = zp[1];
      const float4 ha = hp[0], hb = hp[1];
      const float4 wa = wp[0], wb = wp[1];
      float v[8] = {za.x + ha.x, za.y + ha.y, za.z + ha.z, za.w + ha.w,
                    zb.x + hb.x, zb.y + hb.y, zb.z + hb.z, zb.w + hb.w};
      float w[8] = {wa.x, wa.y, wa.z, wa.w, wb.x, wb.y, wb.z, wb.w};
      float sv = 0.f, sw = 0.f;
#pragma unroll
      for (int i = 0; i < 8; ++i) { sv += v[i]; sw += w[i]; }
#pragma unroll
      for (int off = 8; off > 0; off >>= 1) {
        sv += __shfl_down(sv, off, 16);
        sw += __shfl_down(sw, off, 16);
      }
      sv = __shfl(sv, lane & 48);   // broadcast from 16-group leader
      sw = __shfl(sw, lane & 48);
      const float muv = sv * (1.f / 128.f), muw = sw * (1.f / 128.f);
      const float gw = gn_w[hq];
      float4 o0, o1, p0, p1;
      o0.x = (v[0] - muv) * gw; o0.y = (v[1] - muv) * gw;
      o0.z = (v[2] - muv) * gw; o0.w = (v[3] - muv) * gw;
      o1.x = (v[4] - muv) * gw; o1.y = (v[5] - muv) * gw;
      o1.z = (v[6] - muv) * gw; o1.w = (v[7] - muv) * gw;
      p0.x = (w[0] - muw) * gw; p0.y = (w[1] - muw) * gw;
      p0.z = (w[2] - muw) * gw; p0.w = (w[3] - muw) * gw;
      p1.x = (w[4] - muw) * gw; p1.y = (w[5] - muw) * gw;
      p1.z = (w[6] - muw) * gw; p1.w = (w[7] - muw) * gw;
      *(float4*)&vtgL[bh16 * 128 + dbase]     = o0;
      *(float4*)&vtgL[bh16 * 128 + dbase + 4] = o1;
      *(float4*)&wtgL[bh16 * 128 + dbase]     = p0;
      *(float4*)&wtgL[bh16 * 128 + dbase + 4] = p1;
    }
    __syncthreads();

    const int wave = tid >> 6, lane = tid & 63;
    const int n = (blk - 16) * 4 + wave;
    const float4* row = (const float4*)(W_y + (size_t)n * DIM);
    const int half = lane >> 5, l32 = lane & 31;
    float cc = 0.f;
#pragma unroll
    for (int p = 0; p < 4; ++p) {
      const int h = p * 2 + half;
      float4 wv = row[p * 64 + lane];
      const float4 va = *(const float4*)&vtgL[h * 128 + l32 * 4];
      const float4 vb = *(const float4*)&vtgL[(8 + h) * 128 + l32 * 4];
      const float4 wa = *(const float4*)&wtgL[h * 128 + l32 * 4];
      const float4 wb = *(const float4*)&wtgL[(8 + h) * 128 + l32 * 4];
      float gv0 = wv.x * va.x + wv.y * va.y + wv.z * va.z + wv.w * va.w;
      float gv1 = wv.x * vb.x + wv.y * vb.y + wv.z * vb.z + wv.w * vb.w;
      float gw0 = wv.x * wa.x + wv.y * wa.y + wv.z * wa.z + wv.w * wa.w;
      float gw1 = wv.x * wb.x + wv.y * wb.y + wv.z * wb.z + wv.w * wb.w;
      cc += (wv.x + wv.y + wv.z + wv.w) * gn_b[h];
#pragma unroll
      for (int off = 16; off > 0; off >>= 1) {
        gv0 += __shfl_down(gv0, off, 32);
        gv1 += __shfl_down(gv1, off, 32);
        gw0 += __shfl_down(gw0, off, 32);
        gw1 += __shfl_down(gw1, off, 32);
      }
      if (l32 == 0) {
        Gv[(size_t)h * DIM + n]       = gv0;
        Gv[(size_t)(8 + h) * DIM + n] = gv1;
        Gw[(size_t)h * DIM + n]       = gw0;
        Gw[(size_t)(8 + h) * DIM + n] = gw1;
      }
    }
    for (int off = 32; off > 0; off >>= 1) cc += __shfl_down(cc, off);
    if (lane == 0) constc[n] = b_y[n] + cc;
  }
}

// ---- finalize: y[m,n] = (constc[n] + sum_k alpha2[m,k]*G[k,n]) * Sy[m,n], in place ----
__global__ __launch_bounds__(256) void finalize(const float* __restrict__ alpha2,
                                                const float* __restrict__ Gv,
                                                const float* __restrict__ Gw,
                                                const float* __restrict__ constc,
                                                float* __restrict__ y) {
  const int tid = threadIdx.x;
  const int n0 = blockIdx.x * 256;
  const int m0 = blockIdx.y * 64;
  const int b = m0 >> 11;
  __shared__ float aS[64 * 16];
  ((float4*)aS)[tid] = ((const float4*)(alpha2 + (size_t)m0 * 16))[tid];
  __syncthreads();
  const int c = tid & 63;     // col4 within n-tile
  const int rg = tid >> 6;    // row group (16 rows each)
  const int n = n0 + c * 4;
  f32x4 g[16 * 2];
#pragma unroll
  for (int h = 0; h < 8; ++h) {
    g[2 * h]     = *(const f32x4*)&Gv[(size_t)(b * NH + h) * DIM + n];
    g[2 * h + 1] = *(const f32x4*)&Gw[(size_t)(b * NH + h) * DIM + n];
  }
  const f32x4 cc = *(const f32x4*)&constc[n];
#pragma unroll
  for (int jj = 0; jj < 16; ++jj) {
    const int m = m0 + rg * 16 + jj;
    const float* a = &aS[(rg * 16 + jj) * 16];
    f32x4 Ay = cc;
#pragma unroll
    for (int k = 0; k < 16; ++k) Ay += a[k] * g[k];
    f32x4 s = *(const f32x4*)&y[(size_t)m * DIM + n];
    *(f32x4*)&y[(size_t)m * DIM + n] = Ay * s;
  }
}

extern "C" void kernel_launch(void* const* d_in, const int* in_sizes, int n_in,
                              void* d_out, int out_size, void* d_ws, size_t ws_size,
                              hipStream_t stream) {
  const float* x      = (const float*)d_in[0];
  const float* hidden = (const float*)d_in[1];
  const float* W_z    = (const float*)d_in[2];
  const float* b_z    = (const float*)d_in[3];
  const float* W_za   = (const float*)d_in[4];
  const float* b_za   = (const float*)d_in[5];
  const float* W_y    = (const float*)d_in[6];
  const float* b_y    = (const float*)d_in[7];
  const float* W_ya   = (const float*)d_in[8];
  const float* b_ya   = (const float*)d_in[9];
  const float* W_dt   = (const float*)d_in[10];
  const float* b_dt   = (const float*)d_in[11];
  const float* ln_a   = (const float*)d_in[12];
  const float* gn_w   = (const float*)d_in[13];
  const float* gn_b   = (const float*)d_in[14];

  char* ws = (char*)d_ws;
  unsigned short* xb   = (unsigned short*)(ws);             // 8,388,608 B
  unsigned short* Wzb  = (unsigned short*)(ws + 8388608);   // 2,097,152 B
  unsigned short* Wzab = (unsigned short*)(ws + 10485760);  // 2,097,152 B
  unsigned short* Wyab = (unsigned short*)(ws + 12582912);  // 2,097,152 B
  float* ln_da  = (float*)(ws + 14680064);                  // 131,072 B
  float* Zs     = (float*)(ws + 14811136);                  // 8,192 B
  float* wdiag  = (float*)(ws + 14819328);                  // 8,192 B
  float* Gv     = (float*)(ws + 14843904);                  // 65,536 B
  float* Gw     = (float*)(ws + 14909440);                  // 65,536 B
  float* constc = (float*)(ws + 14974976);                  // 4,096 B
  float* alpha2 = (float*)(ws + 14979072);                  // 262,144 B

  float* y = (float*)d_out;
  float* hidden_next = y + (size_t)M_TOT * DIM;

  prep_kernel<<<7168, 256, 0, stream>>>(x, W_dt, b_dt, ln_a,
                                        (const float4*)W_z, (const float4*)W_za,
                                        (const float4*)W_ya,
                                        ln_da, xb, (ushort4*)Wzb, (ushort4*)Wzab,
                                        (ushort4*)Wyab, Zs);

  gemm_all<<<768, 256, 0, stream>>>(xb, Wzb, Wzab, Wyab,
                                    b_z, b_za, b_ya, Zs, wdiag, y);

  proj_scan<<<272, 256, 0, stream>>>(Zs, hidden, wdiag, gn_w, ln_da,
                                     alpha2, hidden_next,
                                     W_y, gn_b, b_y, Gv, Gw, constc);

  finalize<<<dim3(4, 64), 256, 0, stream>>>(alpha2, Gv, Gw, constc, y);
}